// Round 2
// baseline (371.590 us; speedup 1.0000x reference)
//
#include <hip/hip_runtime.h>

#define TWOPI_256 0.024543692606170259f  // 2*pi/256

// ---------------- Kernel 1: per (b,ci) image -> 32x16 spectral modes ----------------
// Stage A: P[h][k] = sum_w x[h][w] * e^{-2pi i k w/256}, k in [0,16)
// Stage B: Xm[t][k] = sum_h P[h][k] * e^{-2pi i ky_t h/256}, ky_t = t (t<16) or 240+t-16
// Xm layout: [t][k][ci][b] float2
__global__ __launch_bounds__(256) void k1_fwd(const float* __restrict__ x,
                                              float2* __restrict__ Xm) {
  const int blk = blockIdx.x;  // b*64 + ci
  const int tid = threadIdx.x;

  __shared__ float tabc[256];
  __shared__ float tabs[256];
  __shared__ float xT[16][256];   // [w within chunk][h]
  __shared__ float Pbf[8704];     // swizzled: f(k,h,c) = k*544 + 4*(k&7) + 2*h + c

  {
    float s, c;
    sincosf((float)tid * TWOPI_256, &s, &c);
    tabc[tid] = c;
    tabs[tid] = s;
  }

  const int hg = tid >> 2;  // 0..63 -> h = hg*4+i
  const int kg = tid & 3;   // 0..3  -> k = kg*4+j

  float accr[4][4], acci[4][4];
#pragma unroll
  for (int i = 0; i < 4; ++i)
#pragma unroll
    for (int j = 0; j < 4; ++j) { accr[i][j] = 0.f; acci[i][j] = 0.f; }

  const float4* xrow = (const float4*)(x + ((size_t)blk << 16) + tid * 256);
  float4 vld[4];
#pragma unroll
  for (int q = 0; q < 4; ++q) vld[q] = xrow[q];

  __syncthreads();  // tables ready

  float cr[4], sr[4];
#pragma unroll
  for (int j = 0; j < 4; ++j) {
    const int k = kg * 4 + j;
    cr[j] = tabc[k];
    sr[j] = tabs[k];
  }

  for (int wc = 0; wc < 16; ++wc) {
    __syncthreads();
#pragma unroll
    for (int q = 0; q < 4; ++q) {
      xT[q * 4 + 0][tid] = vld[q].x;
      xT[q * 4 + 1][tid] = vld[q].y;
      xT[q * 4 + 2][tid] = vld[q].z;
      xT[q * 4 + 3][tid] = vld[q].w;
    }
    if (wc < 15) {
#pragma unroll
      for (int q = 0; q < 4; ++q) vld[q] = xrow[(wc + 1) * 4 + q];
    }
    __syncthreads();

    const int w0 = wc * 16;
    float c[4], s[4];
#pragma unroll
    for (int j = 0; j < 4; ++j) {
      const int idx = ((kg * 4 + j) * w0) & 255;
      c[j] = tabc[idx];
      s[j] = tabs[idx];
    }
#pragma unroll 4
    for (int wi = 0; wi < 16; ++wi) {
      const float4 xv = *(const float4*)&xT[wi][hg * 4];
#pragma unroll
      for (int j = 0; j < 4; ++j) {
        accr[0][j] += xv.x * c[j]; acci[0][j] -= xv.x * s[j];
        accr[1][j] += xv.y * c[j]; acci[1][j] -= xv.y * s[j];
        accr[2][j] += xv.z * c[j]; acci[2][j] -= xv.z * s[j];
        accr[3][j] += xv.w * c[j]; acci[3][j] -= xv.w * s[j];
        const float cn = c[j] * cr[j] - s[j] * sr[j];
        const float sn = s[j] * cr[j] + c[j] * sr[j];
        c[j] = cn; s[j] = sn;
      }
    }
  }

  // write P to swizzled LDS
#pragma unroll
  for (int j = 0; j < 4; ++j) {
    const int k = kg * 4 + j;
    const int base = k * 544 + 4 * (k & 7) + 8 * hg;  // 2*(hg*4)
    *(float4*)&Pbf[base]     = make_float4(accr[0][j], acci[0][j], accr[1][j], acci[1][j]);
    *(float4*)&Pbf[base + 4] = make_float4(accr[2][j], acci[2][j], accr[3][j], acci[3][j]);
  }
  __syncthreads();

  // Stage B: thread = (k, tt); handles t = tt and t = tt+16 (ky = tt, 240+tt)
  const int k = tid & 15;
  const int tt = tid >> 4;  // 0..15
  const int pbase = k * 544 + 4 * (k & 7);
  float c0 = 1.f, s0 = 0.f, c1 = 1.f, s1 = 0.f;
  const float cr0 = tabc[tt], sr0 = tabs[tt];
  const float cr1 = tabc[240 + tt], sr1 = tabs[240 + tt];
  float X0r = 0.f, X0i = 0.f, X1r = 0.f, X1i = 0.f;
  for (int h = 0; h < 256; h += 2) {
    const float4 pv = *(const float4*)&Pbf[pbase + 2 * h];
    // (Pr + i Pi)(c - i s): re = Pr*c + Pi*s, im = Pi*c - Pr*s
    X0r += pv.x * c0 + pv.y * s0; X0i += pv.y * c0 - pv.x * s0;
    X1r += pv.x * c1 + pv.y * s1; X1i += pv.y * c1 - pv.x * s1;
    float cn = c0 * cr0 - s0 * sr0, sn = s0 * cr0 + c0 * sr0; c0 = cn; s0 = sn;
    cn = c1 * cr1 - s1 * sr1; sn = s1 * cr1 + c1 * sr1; c1 = cn; s1 = sn;
    X0r += pv.z * c0 + pv.w * s0; X0i += pv.w * c0 - pv.z * s0;
    X1r += pv.z * c1 + pv.w * s1; X1i += pv.w * c1 - pv.z * s1;
    cn = c0 * cr0 - s0 * sr0; sn = s0 * cr0 + c0 * sr0; c0 = cn; s0 = sn;
    cn = c1 * cr1 - s1 * sr1; sn = s1 * cr1 + c1 * sr1; c1 = cn; s1 = sn;
  }
  const int ci = blk & 63, b = blk >> 6;
  Xm[((tt * 16 + k) * 64 + ci) * 8 + b]        = make_float2(X0r, X0i);
  Xm[(((tt + 16) * 16 + k) * 64 + ci) * 8 + b] = make_float2(X1r, X1i);
}

// ---------------- Kernel 2: per (t,k): channel mixing + pair products + scaling ----
// Am layout: [b][o][t][k] float2, scaled by alpha_k = (k==0?1:2)/65536
__global__ __launch_bounds__(256) void k2_mix(const float2* __restrict__ Xm,
                                              const float* __restrict__ w1r,
                                              const float* __restrict__ w1i,
                                              const float* __restrict__ w2r,
                                              const float* __restrict__ w2i,
                                              float2* __restrict__ Am) {
  const int blk = blockIdx.x;  // t*16 + k
  const int t = blk >> 4, k = blk & 15;
  const int tp = t & 15;
  const float* __restrict__ wr = (t < 16) ? w1r : w2r;
  const float* __restrict__ wi = (t < 16) ? w1i : w2i;
  const int tid = threadIdx.x;

  __shared__ float2 Xs[64][8];  // [i][b]
  __shared__ float2 Cb[64][8];  // [o][b]

  {
    const float2* src = Xm + ((size_t)blk << 9);
    float2* dst = &Xs[0][0];
    dst[tid] = src[tid];
    dst[tid + 256] = src[tid + 256];
  }
  __syncthreads();

  // 480 mixing work-items (o in [0,60) x b in [0,8)) over 256 threads
  for (int n = tid; n < 480; n += 256) {
    const int o = n >> 3, bb = n & 7;
    const int wofs = o * 256 + tp * 16 + k;
    float ar = 0.f, ai = 0.f;
#pragma unroll 4
    for (int i = 0; i < 64; ++i) {
      const float wrv = wr[i * 15360 + wofs];  // (i*60+o)*256 + tp*16 + k
      const float wiv = wi[i * 15360 + wofs];
      const float2 xv = Xs[i][bb];
      ar += xv.x * wrv - xv.y * wiv;
      ai += xv.x * wiv + xv.y * wrv;
    }
    Cb[o][bb] = make_float2(ar, ai);
  }
  __syncthreads();
  if (tid < 32) {
    const int p = tid >> 3, bb = tid & 7;
    const float2 u = Cb[2 * p][bb], v = Cb[2 * p + 1][bb];
    Cb[60 + p][bb] = make_float2(u.x * v.x - u.y * v.y, u.x * v.y + u.y * v.x);
  }
  __syncthreads();
  const float alpha = (k == 0 ? 1.f : 2.f) * (1.f / 65536.f);
#pragma unroll
  for (int n = tid; n < 512; n += 256) {
    const int o = n >> 3, bb = n & 7;
    const float2 v = Cb[o][bb];
    Am[(((size_t)(bb * 64 + o)) * 32 + t) * 16 + k] = make_float2(v.x * alpha, v.y * alpha);
  }
}

// ---------------- Kernel 3: per (b,o): inverse H-DFT then real inverse W ----------
__device__ __forceinline__ unsigned int bfp(float a) {
  return (__float_as_uint(a) + 0x8000u) >> 16;
}

__global__ __launch_bounds__(256) void k3_inv(const float2* __restrict__ Am,
                                              float* __restrict__ out) {
  const int blk = blockIdx.x;  // b*64 + o
  const int tid = threadIdx.x;

  __shared__ float tabc[256];
  __shared__ float tabs[256];
  __shared__ float2 Ams[32][16];
  __shared__ unsigned short Zt[32][264];  // bf16, row j = (2k:Re, 2k+1:Im)
  __shared__ float Tt[10240];             // T[j][w], swizzled: j*320 + (w>>4)*20 + (w&15)

  {
    float s, c;
    sincosf((float)tid * TWOPI_256, &s, &c);
    tabc[tid] = c;
    tabs[tid] = s;
  }
  {
    const float2* src = Am + ((size_t)blk << 9);
    float2* dst = &Ams[0][0];
    dst[tid] = src[tid];
    dst[tid + 256] = src[tid + 256];
  }
  __syncthreads();

  // T[2k][w] = cos(2pi k w/256); T[2k+1][w] = -sin(2pi k w/256)
#pragma unroll
  for (int j = 0; j < 32; ++j) {
    const int w = tid;
    const int idx = ((j >> 1) * w) & 255;
    const float val = (j & 1) ? -tabs[idx] : tabc[idx];
    Tt[j * 320 + (w >> 4) * 20 + (w & 15)] = val;
  }

  // Stage D: Z[h][k] = sum_t Am[t][k] * e^{+2pi i ky_t h/256}
  const int hg = tid >> 2, kg = tid & 3;
  float Zr[4][4], Zi[4][4];
#pragma unroll
  for (int i = 0; i < 4; ++i)
#pragma unroll
    for (int j = 0; j < 4; ++j) { Zr[i][j] = 0.f; Zi[i][j] = 0.f; }
  float ch[4], sh[4], crh[4], srh[4];
#pragma unroll
  for (int i = 0; i < 4; ++i) {
    const int h = hg * 4 + i;
    crh[i] = tabc[h];
    srh[i] = tabs[h];
    ch[i] = 1.f;
    sh[i] = 0.f;
  }
  for (int t = 0; t < 32; ++t) {
    if (t == 16) {
#pragma unroll
      for (int i = 0; i < 4; ++i) {
        const int idx = (240 * (hg * 4 + i)) & 255;
        ch[i] = tabc[idx];
        sh[i] = tabs[idx];
      }
    }
    const float4 a01 = *(const float4*)&Ams[t][kg * 4];
    const float4 a23 = *(const float4*)&Ams[t][kg * 4 + 2];
    const float Ar[4] = {a01.x, a01.z, a23.x, a23.z};
    const float Ai[4] = {a01.y, a01.w, a23.y, a23.w};
#pragma unroll
    for (int i = 0; i < 4; ++i) {
#pragma unroll
      for (int j = 0; j < 4; ++j) {
        Zr[i][j] += Ar[j] * ch[i] - Ai[j] * sh[i];
        Zi[i][j] += Ar[j] * sh[i] + Ai[j] * ch[i];
      }
      const float cn = ch[i] * crh[i] - sh[i] * srh[i];
      const float sn = sh[i] * crh[i] + ch[i] * srh[i];
      ch[i] = cn;
      sh[i] = sn;
    }
  }
#pragma unroll
  for (int j = 0; j < 4; ++j) {
    const int kk = kg * 4 + j;
    const unsigned int p0 = bfp(Zr[0][j]) | (bfp(Zr[1][j]) << 16);
    const unsigned int p1 = bfp(Zr[2][j]) | (bfp(Zr[3][j]) << 16);
    *(uint2*)&Zt[2 * kk][hg * 4] = make_uint2(p0, p1);
    const unsigned int q0 = bfp(Zi[0][j]) | (bfp(Zi[1][j]) << 16);
    const unsigned int q1 = bfp(Zi[2][j]) | (bfp(Zi[3][j]) << 16);
    *(uint2*)&Zt[2 * kk + 1][hg * 4] = make_uint2(q0, q1);
  }
  __syncthreads();

  // Stage E: out[h][w] = sum_{j=0}^{31} Z[j][h] * T[j][w]   (8h x 16w register tile)
  const int wg = tid & 15, hg2 = tid >> 4;
  float* outp = out + ((size_t)blk << 16);
  for (int chunk = 0; chunk < 2; ++chunk) {
    const int h0 = chunk * 128 + hg2 * 8;
    float acc[8][16];
#pragma unroll
    for (int ii = 0; ii < 8; ++ii)
#pragma unroll
      for (int ww = 0; ww < 16; ++ww) acc[ii][ww] = 0.f;
    for (int j = 0; j < 32; ++j) {
      const uint4 zp = *(const uint4*)&Zt[j][h0];
      float zv[8];
      zv[0] = __uint_as_float(zp.x << 16);
      zv[1] = __uint_as_float(zp.x & 0xffff0000u);
      zv[2] = __uint_as_float(zp.y << 16);
      zv[3] = __uint_as_float(zp.y & 0xffff0000u);
      zv[4] = __uint_as_float(zp.z << 16);
      zv[5] = __uint_as_float(zp.z & 0xffff0000u);
      zv[6] = __uint_as_float(zp.w << 16);
      zv[7] = __uint_as_float(zp.w & 0xffff0000u);
      const float* tb = &Tt[j * 320 + wg * 20];
      const float4 t0 = *(const float4*)&tb[0];
      const float4 t1 = *(const float4*)&tb[4];
      const float4 t2 = *(const float4*)&tb[8];
      const float4 t3 = *(const float4*)&tb[12];
      const float tv[16] = {t0.x, t0.y, t0.z, t0.w, t1.x, t1.y, t1.z, t1.w,
                            t2.x, t2.y, t2.z, t2.w, t3.x, t3.y, t3.z, t3.w};
#pragma unroll
      for (int ii = 0; ii < 8; ++ii)
#pragma unroll
        for (int ww = 0; ww < 16; ++ww) acc[ii][ww] += zv[ii] * tv[ww];
    }
#pragma unroll
    for (int ii = 0; ii < 8; ++ii) {
      float* row = outp + (size_t)(h0 + ii) * 256 + wg * 16;
      *(float4*)&row[0]  = make_float4(acc[ii][0], acc[ii][1], acc[ii][2], acc[ii][3]);
      *(float4*)&row[4]  = make_float4(acc[ii][4], acc[ii][5], acc[ii][6], acc[ii][7]);
      *(float4*)&row[8]  = make_float4(acc[ii][8], acc[ii][9], acc[ii][10], acc[ii][11]);
      *(float4*)&row[12] = make_float4(acc[ii][12], acc[ii][13], acc[ii][14], acc[ii][15]);
    }
  }
}

extern "C" void kernel_launch(void* const* d_in, const int* in_sizes, int n_in,
                              void* d_out, int out_size, void* d_ws, size_t ws_size,
                              hipStream_t stream) {
  const float* x   = (const float*)d_in[0];
  const float* w1r = (const float*)d_in[1];
  const float* w1i = (const float*)d_in[2];
  const float* w2r = (const float*)d_in[3];
  const float* w2i = (const float*)d_in[4];
  float* out = (float*)d_out;

  float2* Xm = (float2*)d_ws;          // 32*16*64*8 float2 = 2 MB
  float2* Am = Xm + 262144;            // 8*64*32*16 float2 = 2 MB

  k1_fwd<<<dim3(512), dim3(256), 0, stream>>>(x, Xm);
  k2_mix<<<dim3(512), dim3(256), 0, stream>>>(Xm, w1r, w1i, w2r, w2i, Am);
  k3_inv<<<dim3(512), dim3(256), 0, stream>>>(Am, out);
}